// Round 1
// 869.405 us; speedup vs baseline: 1.1916x; 1.1916x over previous
//
#include <hip/hip_runtime.h>
#include <cmath>

// Problem: B=16, S=512, H=1024, NH=16, DH=64.
// out = [ctx 16x512x1024][scores 16x16x512x512], fp32.
// Strategy: split-fp32 (hi/lo bf16, 3-term MFMA) for all GEMM-shaped work.
//   x = hi(trunc) + lo(rne residual); A*B ~= Ah*Bh + Ah*Bl + Al*Bh (err ~2^-17).
// Masked scores written as -1e30 (finite; exp(-1e30 - m) == 0 so softmax ok).
//
// R1 changes vs previous (1036 us):
//  * X / W split to hi/lo planes ONCE (memory-bound pass) instead of per-tile
//    VALU conversion inside qkv (which re-converted X 8x, W 64x). qkv now
//    stages pre-split planes with global_load_lds dwordx4 (m97 pattern),
//    BK=32, hi/lo interleaved in one 8-group swizzled row -> 32 KB LDS,
//    3 blocks/CU.
//  * V transposed ONCE in global (vtrans) instead of 32 scalar ds_write_u16
//    per thread per chunk in attn (and 8x redundantly across q-tiles).
//  * attn stages K and V^T via global_load_lds (pre-swizzled global source,
//    linear LDS dest); Q staged through the K buffers. LDS 69.6 -> 51.2 KB
//    -> 3 blocks/CU (occupancy 24% -> 36%).
//  * Scratch planes (X/W/V-untransposed) live in the sc output region (dead
//    until attn); d_ws usage stays at the previous 100.66 MB.

typedef __bf16 bf16x8 __attribute__((ext_vector_type(8)));
typedef float  f32x4  __attribute__((ext_vector_type(4)));

#define MFMA(a, b, c) __builtin_amdgcn_mfma_f32_16x16x32_bf16(a, b, c, 0, 0, 0)
#define NEG_BIG (-1e30f)

static __device__ __forceinline__ unsigned pk_hi(float a, float b) {
    // two truncated-bf16 his packed little-endian (a -> low)
    return (__float_as_uint(a) >> 16) | (__float_as_uint(b) & 0xFFFF0000u);
}
static __device__ __forceinline__ float trf(float x) {
    return __uint_as_float(__float_as_uint(x) & 0xFFFF0000u);
}
static __device__ __forceinline__ unsigned rne16(float x) {
    unsigned b = __float_as_uint(x);
    return (b + 0x7FFFu + ((b >> 16) & 1u)) >> 16;
}
static __device__ __forceinline__ ushort hi16(float x) {
    return (ushort)(__float_as_uint(x) >> 16);
}
// Swizzled LDS fragment read: tile stored as [row][8 groups of 8 bf16],
// group XOR-swizzled by (row&7) so ds_read_b128 is bank-uniform.
static __device__ __forceinline__ bf16x8 ldfrag(const ushort* base, int row, int grp) {
    return *(const bf16x8*)(base + (((row << 3) + (grp ^ (row & 7))) << 3));
}
// Direct global->LDS 16B: LDS dest = wave-uniform base + lane*16 (linear);
// the swizzle is applied on the PER-LANE GLOBAL source address instead.
static __device__ __forceinline__ void gl_lds16(const ushort* g, ushort* l) {
    __builtin_amdgcn_global_load_lds(
        (const __attribute__((address_space(1))) void*)g,
        (__attribute__((address_space(3))) void*)l, 16, 0, 0);
}

// ---------------------------------------------------------------------------
// K0: fp32 -> (hi trunc bf16, lo rne residual bf16) planes. 8 elems/thread.
// ---------------------------------------------------------------------------
__global__ __launch_bounds__(256) void split_planes(
    const float* __restrict__ in, ushort* __restrict__ oh,
    ushort* __restrict__ ol, int n8)
{
    for (int i = blockIdx.x * 256 + threadIdx.x; i < n8; i += gridDim.x * 256) {
        float4 f0 = ((const float4*)in)[2 * i], f1 = ((const float4*)in)[2 * i + 1];
        uint4 hv, lv;
        hv.x = pk_hi(f0.x, f0.y); hv.y = pk_hi(f0.z, f0.w);
        hv.z = pk_hi(f1.x, f1.y); hv.w = pk_hi(f1.z, f1.w);
        lv.x = rne16(f0.x - trf(f0.x)) | (rne16(f0.y - trf(f0.y)) << 16);
        lv.y = rne16(f0.z - trf(f0.z)) | (rne16(f0.w - trf(f0.w)) << 16);
        lv.z = rne16(f1.x - trf(f1.x)) | (rne16(f1.y - trf(f1.y)) << 16);
        lv.w = rne16(f1.z - trf(f1.z)) | (rne16(f1.w - trf(f1.w)) << 16);
        ((uint4*)oh)[i] = hv;
        ((uint4*)ol)[i] = lv;
    }
}

// ---------------------------------------------------------------------------
// K1: projection C = X @ W^T + bias from pre-split planes.
// 128x128 tile, BK=32, 4 waves, per-wave 64x64 via 4x4 grid of 16x16x32 MFMA.
// LDS row layout: 8 groups of 16B = [hi k-grp 0..3 | lo k-grp 0..3], XOR(r&7).
// Staging via global_load_lds (linear dest, pre-swizzled per-lane source).
// ---------------------------------------------------------------------------
__global__ __launch_bounds__(256, 3) void qkv_mfma(
    const ushort* __restrict__ xh, const ushort* __restrict__ xl,
    const ushort* __restrict__ wh, const ushort* __restrict__ wl,
    const float* __restrict__ bias, ushort* __restrict__ oh, ushort* __restrict__ ol)
{
    __shared__ __align__(16) ushort As[8192], Bs[8192];
    const int n0 = blockIdx.x * 128, m0 = blockIdx.y * 128;
    const int t = threadIdx.x, w = t >> 6, lane = t & 63;
    const int quad = lane >> 4, l15 = lane & 15;
    const int wr = w >> 1, wc = w & 1;

    const f32x4 zero = {0.f, 0.f, 0.f, 0.f};
    f32x4 acc[4][4];
#pragma unroll
    for (int i = 0; i < 4; ++i)
#pragma unroll
        for (int j = 0; j < 4; ++j) acc[i][j] = zero;

    for (int kc = 0; kc < 1024; kc += 32) {
        __syncthreads();
#pragma unroll
        for (int rep = 0; rep < 8; ++rep) {
            int slot = t + (rep & 3) * 256;         // 1024 slots: 128 rows x 8 grp
            int r = slot >> 3, gs = slot & 7;
            int g = gs ^ (r & 7);                   // global group this slot holds
            int kg = g & 3;                         // k-subgroup (8 bf16)
            if (rep < 4) {
                const ushort* base = (g & 4) ? xl : xh;
                gl_lds16(base + (size_t)(m0 + r) * 1024 + kc + kg * 8,
                         &As[((rep & 3) * 256 + w * 64) * 8]);
            } else {
                const ushort* base = (g & 4) ? wl : wh;
                gl_lds16(base + (size_t)(n0 + r) * 1024 + kc + kg * 8,
                         &Bs[((rep & 3) * 256 + w * 64) * 8]);
            }
        }
        __syncthreads();
        bf16x8 ah[4], al4[4], bh4[4], bl4[4];
#pragma unroll
        for (int i = 0; i < 4; ++i) {
            int row = wr * 64 + i * 16 + l15;
            ah[i]  = ldfrag(As, row, quad);         // hi: groups 0..3
            al4[i] = ldfrag(As, row, 4 + quad);     // lo: groups 4..7
        }
#pragma unroll
        for (int j = 0; j < 4; ++j) {
            int row = wc * 64 + j * 16 + l15;
            bh4[j] = ldfrag(Bs, row, quad);
            bl4[j] = ldfrag(Bs, row, 4 + quad);
        }
#pragma unroll
        for (int i = 0; i < 4; ++i)
#pragma unroll
            for (int j = 0; j < 4; ++j) {
                acc[i][j] = MFMA(ah[i],  bh4[j], acc[i][j]);
                acc[i][j] = MFMA(ah[i],  bl4[j], acc[i][j]);
                acc[i][j] = MFMA(al4[i], bh4[j], acc[i][j]);
            }
    }
    // epilogue: bias, split to hi/lo bf16, store to [bh][s][dd] planes.
#pragma unroll
    for (int j = 0; j < 4; ++j) {
        int n = n0 + wc * 64 + j * 16 + l15;
        float bb = bias[n];
        int h = n >> 6, dd = n & 63;
#pragma unroll
        for (int i = 0; i < 4; ++i)
#pragma unroll
            for (int reg = 0; reg < 4; ++reg) {
                int m = m0 + wr * 64 + i * 16 + quad * 4 + reg;
                int b = m >> 9, s = m & 511;
                float c = acc[i][j][reg] + bb;
                size_t o = (((size_t)(b * 16 + h)) * 512 + s) * 64 + dd;
                oh[o] = hi16(c);
                ol[o] = (ushort)rne16(c - trf(c));
            }
    }
}

// ---------------------------------------------------------------------------
// K2: V plane transpose [bh][s][dd] -> [bh][dd][s], both hi/lo planes.
// 64x64 tile per block via padded LDS (scatter-write, vector read).
// ---------------------------------------------------------------------------
__global__ __launch_bounds__(256, 2) void vtrans(
    const ushort* __restrict__ vh, const ushort* __restrict__ vl,
    ushort* __restrict__ vth, ushort* __restrict__ vtl)
{
    __shared__ __align__(16) ushort Th[64 * 72], Tl[64 * 72];
    const int bh = blockIdx.y, s0 = blockIdx.x * 64;
    const int t = threadIdx.x;
#pragma unroll
    for (int rep = 0; rep < 2; ++rep) {
        int slot = t + rep * 256;                   // 512 slots: 8 dd-grp x 64 s
        int g = slot >> 6, r = slot & 63;
        size_t src = ((size_t)bh * 512 + s0 + r) * 64 + g * 8;
        uint4 hv = *(const uint4*)&vh[src];
        uint4 lv = *(const uint4*)&vl[src];
        unsigned ha[4] = {hv.x, hv.y, hv.z, hv.w};
        unsigned la[4] = {lv.x, lv.y, lv.z, lv.w};
#pragma unroll
        for (int e = 0; e < 4; ++e) {
            int dd = g * 8 + e * 2;
            Th[dd * 72 + r]       = (ushort)(ha[e] & 0xFFFFu);
            Th[(dd + 1) * 72 + r] = (ushort)(ha[e] >> 16);
            Tl[dd * 72 + r]       = (ushort)(la[e] & 0xFFFFu);
            Tl[(dd + 1) * 72 + r] = (ushort)(la[e] >> 16);
        }
    }
    __syncthreads();
#pragma unroll
    for (int rep = 0; rep < 2; ++rep) {
        int slot = t + rep * 256;                   // 512 slots: 64 dd x 8 s-grp
        int dd = slot >> 3, g2 = slot & 7;
        size_t dst = ((size_t)bh * 64 + dd) * 512 + s0 + g2 * 8;
        *(uint4*)&vth[dst] = *(const uint4*)&Th[dd * 72 + g2 * 8];
        *(uint4*)&vtl[dst] = *(const uint4*)&Tl[dd * 72 + g2 * 8];
    }
}

// ---------------------------------------------------------------------------
// K3: fused attention per (64-q-row tile, bh): QK^T (3-MFMA) -> scale/mask ->
// sc write -> online softmax * gp -> P via LDS (C->A layout) -> PV (3-MFMA,
// V^T pre-transposed in global). Each of 4 waves owns 16 q-rows.
// K and V^T staged via global_load_lds; Q staged through the K buffers.
// ---------------------------------------------------------------------------
__global__ __launch_bounds__(256, 3) void attn_fused(
    const ushort* __restrict__ qh, const ushort* __restrict__ ql,
    const ushort* __restrict__ kh, const ushort* __restrict__ kl,
    const ushort* __restrict__ vth, const ushort* __restrict__ vtl,
    const int* __restrict__ mask, const float* __restrict__ gp,
    float* __restrict__ sc, float* __restrict__ ctx)
{
    __shared__ __align__(16) ushort Kh[4096], Kl[4096], Vh[4096], Vl[4096];
    __shared__ __align__(16) ushort Ph[4 * 16 * 72], Pl[4 * 16 * 72];

    const int bh = blockIdx.y, b = bh >> 4, h = bh & 15;
    const int q0 = blockIdx.x * 64;
    const int t = threadIdx.x, w = t >> 6, lane = t & 63;
    const int quad = lane >> 4, l15 = lane & 15;

    // stage Q tile through the K buffers (dead until first chunk staging)
#pragma unroll
    for (int rep = 0; rep < 2; ++rep) {
        int slot = t + rep * 256;                   // 512 slots: 64 rows x 8 grp
        int r = slot >> 3, gs = slot & 7, g = gs ^ (r & 7);
        size_t src = ((size_t)bh * 512 + q0 + r) * 64 + g * 8;
        gl_lds16(&qh[src], &Kh[(rep * 256 + w * 64) * 8]);
        gl_lds16(&ql[src], &Kl[(rep * 256 + w * 64) * 8]);
    }
    __syncthreads();
    bf16x8 qfh[2], qfl[2];
    {
        int qrow = w * 16 + l15;
#pragma unroll
        for (int ks = 0; ks < 2; ++ks) {
            qfh[ks] = ldfrag(Kh, qrow, ks * 4 + quad);
            qfl[ks] = ldfrag(Kl, qrow, ks * 4 + quad);
        }
    }

    float m_run[4] = {-INFINITY, -INFINITY, -INFINITY, -INFINITY};
    float l_run[4] = {0.f, 0.f, 0.f, 0.f};
    const f32x4 zero = {0.f, 0.f, 0.f, 0.f};
    f32x4 accO[4];
#pragma unroll
    for (int d = 0; d < 4; ++d) accO[d] = zero;

    ushort* phb = Ph + w * 16 * 72;
    ushort* plb = Pl + w * 16 * 72;
    int rowg[4];
#pragma unroll
    for (int reg = 0; reg < 4; ++reg) rowg[reg] = q0 + w * 16 + quad * 4 + reg;

    for (int c = 0; c < 8; ++c) {
        __syncthreads();   // prior chunk's LDS reads (and Q frag reads) done
        // stage K chunk + V^T chunk (linear dest, pre-swizzled source)
#pragma unroll
        for (int rep = 0; rep < 2; ++rep) {
            int slot = t + rep * 256;
            int r = slot >> 3, gs = slot & 7, g = gs ^ (r & 7);
            size_t ks_ = ((size_t)bh * 512 + c * 64 + r) * 64 + g * 8;
            size_t vs_ = ((size_t)bh * 64 + r) * 512 + c * 64 + g * 8;
            int db = (rep * 256 + w * 64) * 8;
            gl_lds16(&kh[ks_],  &Kh[db]);
            gl_lds16(&kl[ks_],  &Kl[db]);
            gl_lds16(&vth[vs_], &Vh[db]);
            gl_lds16(&vtl[vs_], &Vl[db]);
        }
        __syncthreads();

        // QK^T for this 64-col chunk
        float sv[4][4];                              // [nt][reg]
#pragma unroll
        for (int nt = 0; nt < 4; ++nt) {
            f32x4 a = zero;
#pragma unroll
            for (int ks = 0; ks < 2; ++ks) {
                int krow = nt * 16 + l15;
                bf16x8 kfh = ldfrag(Kh, krow, ks * 4 + quad);
                bf16x8 kfl = ldfrag(Kl, krow, ks * 4 + quad);
                a = MFMA(qfh[ks], kfh, a);
                a = MFMA(qfh[ks], kfl, a);
                a = MFMA(qfl[ks], kfh, a);
            }
            int col = c * 64 + nt * 16 + l15;
#pragma unroll
            for (int reg = 0; reg < 4; ++reg) {
                int row = rowg[reg];
                int mv = mask[(size_t)b * 262144 + (size_t)row * 512 + col];
                float x = a[reg] * 0.125f;
                float val = (mv | (row == col)) ? x : NEG_BIG;
                sc[(size_t)bh * 262144 + (size_t)row * 512 + col] = val;
                sv[nt][reg] = val;
            }
        }
        // online softmax update (per reg = per q-row)
        float alpha[4];
#pragma unroll
        for (int reg = 0; reg < 4; ++reg) {
            float cm = fmaxf(fmaxf(sv[0][reg], sv[1][reg]), fmaxf(sv[2][reg], sv[3][reg]));
            cm = fmaxf(cm, __shfl_xor(cm, 1));
            cm = fmaxf(cm, __shfl_xor(cm, 2));
            cm = fmaxf(cm, __shfl_xor(cm, 4));
            cm = fmaxf(cm, __shfl_xor(cm, 8));
            float mn = fmaxf(m_run[reg], cm);
            alpha[reg] = __expf(m_run[reg] - mn);
            m_run[reg] = mn;
            float rs = 0.f;
#pragma unroll
            for (int nt = 0; nt < 4; ++nt) {
                float e = (sv[nt][reg] > -5e29f) ? __expf(sv[nt][reg] - mn) : 0.f;
                sv[nt][reg] = e;                     // reuse as p (no gp)
                rs += e;
            }
            rs += __shfl_xor(rs, 1);
            rs += __shfl_xor(rs, 2);
            rs += __shfl_xor(rs, 4);
            rs += __shfl_xor(rs, 8);
            l_run[reg] = l_run[reg] * alpha[reg] + rs;
        }
        // P = p * gp -> wave-private LDS (hi/lo), C-layout -> A-layout
#pragma unroll
        for (int nt = 0; nt < 4; ++nt) {
            int col = c * 64 + nt * 16 + l15;
#pragma unroll
            for (int reg = 0; reg < 4; ++reg) {
                float g = gp[(size_t)b * 262144 + (size_t)rowg[reg] * 512 + col];
                float pv = sv[nt][reg] * g;
                int a_ = (quad * 4 + reg) * 72 + nt * 16 + l15;
                phb[a_] = hi16(pv);
                plb[a_] = (ushort)rne16(pv - trf(pv));
            }
        }
        // rescale O by alpha, then accumulate chunk's P@V
#pragma unroll
        for (int d = 0; d < 4; ++d)
#pragma unroll
            for (int reg = 0; reg < 4; ++reg) accO[d][reg] *= alpha[reg];
#pragma unroll
        for (int ks = 0; ks < 2; ++ks) {
            bf16x8 pfh = *(const bf16x8*)&phb[l15 * 72 + ks * 32 + quad * 8];
            bf16x8 pfl = *(const bf16x8*)&plb[l15 * 72 + ks * 32 + quad * 8];
#pragma unroll
            for (int d = 0; d < 4; ++d) {
                bf16x8 vfh = ldfrag(Vh, d * 16 + l15, ks * 4 + quad);
                bf16x8 vfl = ldfrag(Vl, d * 16 + l15, ks * 4 + quad);
                accO[d] = MFMA(pfh, vfh, accO[d]);
                accO[d] = MFMA(pfh, vfl, accO[d]);
                accO[d] = MFMA(pfl, vfh, accO[d]);
            }
        }
    }
    // epilogue: ctx = O / l
#pragma unroll
    for (int reg = 0; reg < 4; ++reg) {
        float inv = 1.f / l_run[reg];
#pragma unroll
        for (int d = 0; d < 4; ++d)
            ctx[((size_t)b * 512 + rowg[reg]) * 1024 + h * 64 + d * 16 + l15] =
                accO[d][reg] * inv;
    }
}

// ---------------------------------------------------------------------------
extern "C" void kernel_launch(void* const* d_in, const int* in_sizes, int n_in,
                              void* d_out, int out_size, void* d_ws, size_t ws_size,
                              hipStream_t stream) {
    const float* hs   = (const float*)d_in[0];
    const int*   mask = (const int*)d_in[1];
    const float* gp   = (const float*)d_in[2];
    const float* Wq   = (const float*)d_in[3];
    const float* bq   = (const float*)d_in[4];
    const float* Wk   = (const float*)d_in[5];
    const float* bk   = (const float*)d_in[6];
    const float* Wv   = (const float*)d_in[7];
    const float* bv   = (const float*)d_in[8];

    float* out = (float*)d_out;
    float* ctx = out;                                  // [16,512,1024]
    float* sc  = out + (size_t)16 * 512 * 1024;        // [16,16,512,512]

    const size_t PL = (size_t)16 * 16 * 512 * 64;      // 8388608 elems/plane
    const size_t WN = (size_t)1024 * 1024;             // 1048576 elems/W-plane

    // persistent planes in d_ws (exactly the previous 100.66 MB footprint)
    ushort* qhp  = (ushort*)d_ws;
    ushort* qlp  = qhp + PL;
    ushort* khp  = qlp + PL;
    ushort* klp  = khp + PL;
    ushort* vthp = klp + PL;
    ushort* vtlp = vthp + PL;

    // pre-attn scratch lives in the sc output region (dead until attn_fused):
    // [xh xl][wq wk wv hi/lo][vh vl] = 79.7 MB << 268.4 MB
    ushort* scr = (ushort*)sc;
    ushort* xh  = scr;
    ushort* xl  = xh + PL;
    ushort* wqh = xl + PL;
    ushort* wql = wqh + WN;
    ushort* wkh = wql + WN;
    ushort* wkl = wkh + WN;
    ushort* wvh = wkl + WN;
    ushort* wvl = wvh + WN;
    ushort* vhp = wvl + WN;
    ushort* vlp = vhp + PL;

    dim3 blk(256);
    split_planes<<<dim3(2048), blk, 0, stream>>>(hs, xh, xl, (int)(PL / 8));
    split_planes<<<dim3(512),  blk, 0, stream>>>(Wq, wqh, wql, (int)(WN / 8));
    split_planes<<<dim3(512),  blk, 0, stream>>>(Wk, wkh, wkl, (int)(WN / 8));
    split_planes<<<dim3(512),  blk, 0, stream>>>(Wv, wvh, wvl, (int)(WN / 8));
    qkv_mfma<<<dim3(8, 64), blk, 0, stream>>>(xh, xl, wqh, wql, bq, qhp, qlp);
    qkv_mfma<<<dim3(8, 64), blk, 0, stream>>>(xh, xl, wkh, wkl, bk, khp, klp);
    qkv_mfma<<<dim3(8, 64), blk, 0, stream>>>(xh, xl, wvh, wvl, bv, vhp, vlp);
    vtrans<<<dim3(8, 256), blk, 0, stream>>>(vhp, vlp, vthp, vtlp);
    attn_fused<<<dim3(8, 256), blk, 0, stream>>>(qhp, qlp, khp, klp, vthp, vtlp,
                                                 mask, gp, sc, ctx);
}